// Round 13
// baseline (444.001 us; speedup 1.0000x reference)
//
#include <hip/hip_runtime.h>
#include <hip/hip_bf16.h>

#define F_IN 128
#define F_OUTV 64
#define NROW 4096

typedef __attribute__((ext_vector_type(8))) short bf16x8;
typedef __attribute__((ext_vector_type(4))) float f32x4;
typedef __attribute__((ext_vector_type(4))) int int4v;
typedef __attribute__((ext_vector_type(4))) float float4v;

static __device__ __forceinline__ short f2bf(float x) {
    __hip_bfloat16 h = __float2bfloat16(x);
    return *reinterpret_cast<short*>(&h);
}

// Kernel 1: h = inp @ W  (fp32), src = h@a1, dst = h@a2, store hT[b][o][m] bf16
__global__ __launch_bounds__(256) void gat_prep(
    const float* __restrict__ inp,    // [4][4096][128]
    const float* __restrict__ W,      // [128][64]
    const float* __restrict__ a,      // [128]
    __hip_bfloat16* __restrict__ hT,  // [4][64][4096]
    float* __restrict__ src,          // [4][4096]
    float* __restrict__ dst)          // [4][4096]
{
    __shared__ float Wl[F_IN * F_OUTV];     // 32 KB
    __shared__ float inl[64][F_IN];         // 32 KB
    __shared__ float hl[64][F_OUTV + 1];    // ~16 KB

    int bid  = blockIdx.x;     // 256 blocks: 4 batches x 64 tiles
    int b    = bid >> 6;
    int tile = bid & 63;
    int n0   = tile * 64;
    int tid  = threadIdx.x;

    for (int i = tid; i < F_IN * F_OUTV; i += 256)
        Wl[i] = W[i];
    const float* ip = inp + ((size_t)b * NROW + n0) * F_IN;
    for (int i = tid; i < 64 * F_IN; i += 256)
        ((float*)inl)[i] = ip[i];
    __syncthreads();

    int o  = tid & 63;            // lane (waves are 64 consecutive threads)
    int rb = (tid >> 6) * 16;     // 16 rows per wave
    for (int r = rb; r < rb + 16; ++r) {
        float s = 0.f;
        #pragma unroll 8
        for (int k = 0; k < F_IN; ++k)
            s += inl[r][k] * Wl[k * F_OUTV + o];
        hl[r][o] = s;
    }
    __syncthreads();

    // src/dst: lanes are o; shuffle-reduce over 64 lanes
    float a1 = a[o], a2 = a[F_OUTV + o];
    for (int r = rb; r < rb + 16; ++r) {
        float h = hl[r][o];
        float s1 = h * a1, s2 = h * a2;
        #pragma unroll
        for (int off = 32; off; off >>= 1) {
            s1 += __shfl_xor(s1, off);
            s2 += __shfl_xor(s2, off);
        }
        if (o == 0) {
            src[(size_t)b * NROW + n0 + r] = s1;
            dst[(size_t)b * NROW + n0 + r] = s2;
        }
    }

    // write hT[b][orow][n0 + i], 16 consecutive bf16 per thread (coalesced)
    int orow = tid >> 2;
    int i0   = (tid & 3) * 16;
    __hip_bfloat16* hp = hT + ((size_t)b * F_OUTV + orow) * NROW + n0 + i0;
    #pragma unroll
    for (int j = 0; j < 16; ++j)
        hp[j] = __float2bfloat16(hl[i0 + j][orow]);
}

// Kernel 2: fused mask + leaky + softmax + PV via MFMA.
// Self-calibrating probes (layout-proof epilogue) + ones-denominator
// (num/den always consistent). 2-deep software pipeline on adj/dst loads
// to raise memory-level parallelism (latency-bound fix).
__global__ __launch_bounds__(256) void gat_attn(
    const int* __restrict__ adj,           // [4][4096][4096]
    const __hip_bfloat16* __restrict__ hT, // [4][64][4096]
    const float* __restrict__ src,
    const float* __restrict__ dst,
    float* __restrict__ out)               // [4][4096][64]
{
    int bid  = blockIdx.x;      // 1024 blocks: 4 batches x 256 row-tiles
    int b    = bid >> 8;
    int tile = bid & 255;
    int n0   = tile * 16;
    int tid  = threadIdx.x;
    int w    = tid >> 6;        // wave: m-slice of 1024
    int l    = tid & 63;
    int row  = l & 15;          // lane's data label: query sub-row / feature sub-col
    int kg   = l >> 4;          // lane's k-group (data-packing side)

    // ---- layout probes: exact in bf16 (labels 0..15, weight 1/32) ----
    bf16x8 lab, inv32, ones;
    #pragma unroll
    for (int j = 0; j < 8; ++j) {
        lab[j]   = f2bf((float)row);
        inv32[j] = (short)0x3D00;   // bf16 1/32
        ones[j]  = (short)0x3F80;   // bf16 1.0
    }
    f32x4 zero4 = {0,0,0,0};
    f32x4 pq = __builtin_amdgcn_mfma_f32_16x16x32_bf16(lab, inv32, zero4, 0, 0, 0);
    f32x4 pf = __builtin_amdgcn_mfma_f32_16x16x32_bf16(inv32, lab, zero4, 0, 0, 0);
    // pq[reg] = query-label of this C slot; pf[reg] = feature-sublabel.

    const float srcv = src[(size_t)b * NROW + n0 + row];
    const float* dstb = dst + (size_t)b * NROW;
    const int* adjp = adj + ((size_t)b * NROW + (n0 + row)) * NROW;
    const __hip_bfloat16* hb = hT + (size_t)b * F_OUTV * NROW;

    f32x4 acc[4] = {{0,0,0,0},{0,0,0,0},{0,0,0,0},{0,0,0,0}};
    f32x4 accd   = {0,0,0,0};

    const int mstart = w * 1024;
    const int kgo = kg * 8;

    // chunk compute: mask+leaky+exp -> bf16 afrag; 1 den + 4 num MFMAs
    auto body = [&](int4v A0, int4v A1, float4v D0, float4v D1, int mb) {
        bf16x8 afrag;
        #pragma unroll
        for (int j = 0; j < 8; ++j) {
            float dv = (j < 4) ? D0[j] : D1[j - 4];
            int   am = (j < 4) ? A0[j] : A1[j - 4];
            float t  = srcv + dv;
            t = (t > 0.f) ? t : 0.2f * t;     // leaky relu (alpha=0.2)
            float pv = __expf(t);
            pv = (am > 0) ? pv : 0.f;         // mask -> exp(-1e12) == 0
            afrag[j] = f2bf(pv);
        }
        accd = __builtin_amdgcn_mfma_f32_16x16x32_bf16(afrag, ones, accd, 0, 0, 0);
        #pragma unroll
        for (int t2 = 0; t2 < 4; ++t2) {
            bf16x8 bfrag = *(const bf16x8*)(hb + ((size_t)(t2 * 16 + row)) * NROW + mb);
            acc[t2] = __builtin_amdgcn_mfma_f32_16x16x32_bf16(afrag, bfrag, acc[t2], 0, 0, 0);
        }
    };

#define LOADCH(A0, A1, D0, D1, mbv)                    \
    do {                                               \
        A0 = *(const int4v*)(adjp + (mbv));            \
        A1 = *(const int4v*)(adjp + (mbv) + 4);        \
        D0 = *(const float4v*)(dstb + (mbv));          \
        D1 = *(const float4v*)(dstb + (mbv) + 4);      \
    } while (0)

    // 2-deep pipeline: named staging sets A (even chunks) and B (odd chunks)
    int4v a0A, a1A, a0B, a1B;
    float4v d0A, d1A, d0B, d1B;
    LOADCH(a0A, a1A, d0A, d1A, mstart + kgo);
    LOADCH(a0B, a1B, d0B, d1B, mstart + 32 + kgo);

    for (int c = 0; c < 32; c += 2) {
        int mbA = mstart + c * 32 + kgo;
        int mbB = mbA + 32;
        body(a0A, a1A, d0A, d1A, mbA);
        if (c + 2 < 32)
            LOADCH(a0A, a1A, d0A, d1A, mstart + (c + 2) * 32 + kgo);
        body(a0B, a1B, d0B, d1B, mbB);
        if (c + 3 < 32)
            LOADCH(a0B, a1B, d0B, d1B, mstart + (c + 3) * 32 + kgo);
    }
#undef LOADCH

    __shared__ float accb[4][16][F_OUTV];   // 16 KB
    __shared__ float lb[4][16];
    #pragma unroll
    for (int reg = 0; reg < 4; ++reg) {
        int qlab = (int)(pq[reg] + 0.5f);   // which query this slot holds
        int flab = (int)(pf[reg] + 0.5f);   // which feature-sublabel it holds
        #pragma unroll
        for (int t = 0; t < 4; ++t)
            accb[w][qlab][t * 16 + flab] = acc[t][reg];
        if (flab == 0)
            lb[w][qlab] = accd[reg];        // den replicated across cols
    }
    __syncthreads();

    // merge 4 wave partials, divide, output leaky(0.01)
    int col = tid & 63;
    int r0  = tid >> 6;
    float* outp = out + ((size_t)b * NROW + n0) * F_OUTV;
    #pragma unroll
    for (int i = 0; i < 4; ++i) {
        int r = r0 * 4 + i;
        float s  = accb[0][r][col] + accb[1][r][col] + accb[2][r][col] + accb[3][r][col];
        float ls = lb[0][r] + lb[1][r] + lb[2][r] + lb[3][r];
        float hp = s / ls;
        hp = (hp > 0.f) ? hp : 0.01f * hp;
        outp[(size_t)r * F_OUTV + col] = hp;
    }
}

extern "C" void kernel_launch(void* const* d_in, const int* in_sizes, int n_in,
                              void* d_out, int out_size, void* d_ws, size_t ws_size,
                              hipStream_t stream) {
    const float* inp = (const float*)d_in[0];
    const int*   adj = (const int*)d_in[1];
    const float* W   = (const float*)d_in[2];
    const float* a   = (const float*)d_in[3];
    float* out = (float*)d_out;

    __hip_bfloat16* hT = (__hip_bfloat16*)d_ws;                       // 2 MB
    float* srcb = (float*)((char*)d_ws + (size_t)4 * F_OUTV * NROW * 2);
    float* dstb = srcb + (size_t)4 * NROW;

    gat_prep<<<256, 256, 0, stream>>>(inp, W, a, hT, srcb, dstb);
    gat_attn<<<1024, 256, 0, stream>>>(adj, hT, srcb, dstb, out);
}

// Round 16
// 430.831 us; speedup vs baseline: 1.0306x; 1.0306x over previous
//
#include <hip/hip_runtime.h>
#include <hip/hip_bf16.h>

#define F_IN 128
#define F_OUTV 64
#define NROW 4096
#define PTILE 32
#define WSTRIDE (F_IN + 4)   // 132 floats = 528 B: 16B-aligned AND bank-conflict-free

typedef __attribute__((ext_vector_type(8))) short bf16x8;
typedef __attribute__((ext_vector_type(4))) float f32x4;
typedef __attribute__((ext_vector_type(4))) int int4v;
typedef __attribute__((ext_vector_type(4))) float float4v;

static __device__ __forceinline__ short f2bf(float x) {
    __hip_bfloat16 h = __float2bfloat16(x);
    return *reinterpret_cast<short*>(&h);
}

// Kernel 1 (v2): h = inp @ W (fp32), src/dst reduces, hT[b][o][m] bf16.
// 512 blocks x 256 thr (32-row tiles): ~12 waves/CU. W transposed in LDS
// (stride 132: 16B-aligned rows, conflict-free b128 reads); inp via
// wave-uniform global loads; src/dst reduced straight from registers.
__global__ __launch_bounds__(256) void gat_prep(
    const float* __restrict__ inp,    // [4][4096][128]
    const float* __restrict__ W,      // [128][64]
    const float* __restrict__ a,      // [128]
    __hip_bfloat16* __restrict__ hT,  // [4][64][4096]
    float* __restrict__ src,          // [4][4096]
    float* __restrict__ dst)          // [4][4096]
{
    __shared__ float WlT[F_OUTV][WSTRIDE];    // ~33.8 KB, transposed W
    __shared__ float hl[PTILE][F_OUTV + 1];   // 8.3 KB

    int bid  = blockIdx.x;     // 512 blocks: 4 batches x 128 tiles
    int b    = bid >> 7;
    int tile = bid & 127;
    int n0   = tile * PTILE;
    int tid  = threadIdx.x;

    for (int i = tid; i < F_IN * F_OUTV; i += 256) {
        int k = i >> 6, o = i & 63;
        WlT[o][k] = W[i];
    }
    __syncthreads();

    int o  = tid & 63;
    int w4 = tid >> 6;
    float a1 = a[o], a2 = a[F_OUTV + o];

    for (int r = w4 * 8; r < w4 * 8 + 8; ++r) {
        const float* iprow = inp + ((size_t)b * NROW + n0 + r) * F_IN;
        float s = 0.f;
        #pragma unroll 8
        for (int k0 = 0; k0 < F_IN / 4; ++k0) {
            float4v wv = *(const float4v*)&WlT[o][k0 * 4];  // 16B-aligned, no conflict
            float4v iv = *(const float4v*)&iprow[k0 * 4];   // wave-uniform
            s += wv[0] * iv[0] + wv[1] * iv[1] + wv[2] * iv[2] + wv[3] * iv[3];
        }
        hl[r][o] = s;
        // src/dst reduce straight from the register value
        float s1 = s * a1, s2 = s * a2;
        #pragma unroll
        for (int off = 32; off; off >>= 1) {
            s1 += __shfl_xor(s1, off);
            s2 += __shfl_xor(s2, off);
        }
        if (o == 0) {
            src[(size_t)b * NROW + n0 + r] = s1;
            dst[(size_t)b * NROW + n0 + r] = s2;
        }
    }
    __syncthreads();

    // hT[b][orow][n0 + q*8 + j] <- hl[q*8+j][orow], 16 B per thread, coalesced
    int orow = tid >> 2;
    int q    = tid & 3;
    bf16x8 v;
    #pragma unroll
    for (int j = 0; j < 8; ++j)
        v[j] = f2bf(hl[q * 8 + j][orow]);
    *(bf16x8*)(hT + ((size_t)b * F_OUTV + orow) * NROW + n0 + q * 8) = v;
}

// Kernel 2: fused mask + leaky + softmax + PV via MFMA (R8/R13-passing body).
// Self-calibrating probes (layout-proof epilogue) + ones-denominator.
__global__ __launch_bounds__(256) void gat_attn(
    const int* __restrict__ adj,           // [4][4096][4096]
    const __hip_bfloat16* __restrict__ hT, // [4][64][4096]
    const float* __restrict__ src,
    const float* __restrict__ dst,
    float* __restrict__ out)               // [4][4096][64]
{
    int bid  = blockIdx.x;      // 1024 blocks: 4 batches x 256 row-tiles
    int b    = bid >> 8;
    int tile = bid & 255;
    int n0   = tile * 16;
    int tid  = threadIdx.x;
    int w    = tid >> 6;        // wave: m-slice of 1024
    int l    = tid & 63;
    int row  = l & 15;          // lane's data label
    int kg   = l >> 4;          // lane's k-group

    // ---- layout probes: exact in bf16 (labels 0..15, weight 1/32) ----
    bf16x8 lab, inv32, ones;
    #pragma unroll
    for (int j = 0; j < 8; ++j) {
        lab[j]   = f2bf((float)row);
        inv32[j] = (short)0x3D00;   // bf16 1/32
        ones[j]  = (short)0x3F80;   // bf16 1.0
    }
    f32x4 zero4 = {0,0,0,0};
    f32x4 pq = __builtin_amdgcn_mfma_f32_16x16x32_bf16(lab, inv32, zero4, 0, 0, 0);
    f32x4 pf = __builtin_amdgcn_mfma_f32_16x16x32_bf16(inv32, lab, zero4, 0, 0, 0);
    // pq[reg] = query-label of this C slot; pf[reg] = feature-sublabel.

    const float srcv = src[(size_t)b * NROW + n0 + row];
    const float* dstb = dst + (size_t)b * NROW;
    const int* adjp = adj + ((size_t)b * NROW + (n0 + row)) * NROW;
    const __hip_bfloat16* hb = hT + (size_t)b * F_OUTV * NROW;

    f32x4 acc[4] = {{0,0,0,0},{0,0,0,0},{0,0,0,0},{0,0,0,0}};
    f32x4 accd   = {0,0,0,0};

    const int mstart = w * 1024;
    for (int c = 0; c < 32; ++c) {
        int mb = mstart + c * 32 + kg * 8;

        int4v   av0 = *(const int4v*)(adjp + mb);
        int4v   av1 = *(const int4v*)(adjp + mb + 4);
        float4v d0  = *(const float4v*)(dstb + mb);
        float4v d1  = *(const float4v*)(dstb + mb + 4);

        bf16x8 afrag;
        #pragma unroll
        for (int j = 0; j < 8; ++j) {
            float dv = (j < 4) ? d0[j] : d1[j - 4];
            int   am = (j < 4) ? av0[j] : av1[j - 4];
            float t  = srcv + dv;
            t = (t > 0.f) ? t : 0.2f * t;     // leaky relu (alpha=0.2)
            float pv = __expf(t);
            pv = (am > 0) ? pv : 0.f;         // mask -> exp(-1e12) == 0
            afrag[j] = f2bf(pv);
        }

        // denominator through the SAME path: den = P @ ones
        accd = __builtin_amdgcn_mfma_f32_16x16x32_bf16(afrag, ones, accd, 0, 0, 0);

        #pragma unroll
        for (int t2 = 0; t2 < 4; ++t2) {
            bf16x8 bfrag = *(const bf16x8*)(hb + ((size_t)(t2 * 16 + row)) * NROW + mb);
            acc[t2] = __builtin_amdgcn_mfma_f32_16x16x32_bf16(afrag, bfrag, acc[t2], 0, 0, 0);
        }
    }

    __shared__ float accb[4][16][F_OUTV];   // 16 KB
    __shared__ float lb[4][16];
    #pragma unroll
    for (int reg = 0; reg < 4; ++reg) {
        int qlab = (int)(pq[reg] + 0.5f);   // which query this slot holds
        int flab = (int)(pf[reg] + 0.5f);   // which feature-sublabel it holds
        #pragma unroll
        for (int t = 0; t < 4; ++t)
            accb[w][qlab][t * 16 + flab] = acc[t][reg];
        if (flab == 0)
            lb[w][qlab] = accd[reg];        // den replicated across cols
    }
    __syncthreads();

    // merge 4 wave partials, divide, output leaky(0.01)
    int col = tid & 63;
    int r0  = tid >> 6;
    float* outp = out + ((size_t)b * NROW + n0) * F_OUTV;
    #pragma unroll
    for (int i = 0; i < 4; ++i) {
        int r = r0 * 4 + i;
        float s  = accb[0][r][col] + accb[1][r][col] + accb[2][r][col] + accb[3][r][col];
        float ls = lb[0][r] + lb[1][r] + lb[2][r] + lb[3][r];
        float hp = s / ls;
        hp = (hp > 0.f) ? hp : 0.01f * hp;
        outp[(size_t)r * F_OUTV + col] = hp;
    }
}

extern "C" void kernel_launch(void* const* d_in, const int* in_sizes, int n_in,
                              void* d_out, int out_size, void* d_ws, size_t ws_size,
                              hipStream_t stream) {
    const float* inp = (const float*)d_in[0];
    const int*   adj = (const int*)d_in[1];
    const float* W   = (const float*)d_in[2];
    const float* a   = (const float*)d_in[3];
    float* out = (float*)d_out;

    __hip_bfloat16* hT = (__hip_bfloat16*)d_ws;                       // 2 MB
    float* srcb = (float*)((char*)d_ws + (size_t)4 * F_OUTV * NROW * 2);
    float* dstb = srcb + (size_t)4 * NROW;

    gat_prep<<<512, 256, 0, stream>>>(inp, W, a, hT, srcb, dstb);
    gat_attn<<<1024, 256, 0, stream>>>(adj, hT, srcb, dstb, out);
}